// Round 10
// baseline (127.340 us; speedup 1.0000x reference)
//
#include <hip/hip_runtime.h>
#include <hip/hip_bf16.h>

#define NBOX  380
#define NLOCS 85
#define NINST 340   // B(4) * NLOCS(85)
#define SPLIT 4     // row-quarter split of each decoder instance

// box index -> location index (from _recon_indices structure)
__device__ __forceinline__ int loc_of_box(int n) {
    if (n < 256) return n >> 2;               // fm=8, 4 boxes/loc
    if (n < 352) return 64 + (n - 256) / 6;   // fm=4, 6 boxes/loc
    if (n < 376) return 80 + (n - 352) / 6;   // fm=2, 6 boxes/loc
    return 84;                                // fm=1, 4 boxes/loc
}

// Per-batch softmax over depths + per-box affine params + rect + compaction.
// 512 threads. Uses sm[0..896).
__device__ void box_params_dev(int b, const float* __restrict__ zwhere,
    const int* __restrict__ zpresent, const float* __restrict__ zdepth,
    float* wgt, float* sxs, float* oxs, float* sys, float* oys,
    int* binst, int* rect, int* cidx, int* cnt, float* sm)
{
    float* sd  = sm;         // 384 (380 used)
    float* red = sm + 384;   // 512
    const int tid = threadIdx.x;

    if (tid < NBOX) {
        int loc = loc_of_box(tid);
        sd[tid] = (zpresent[b * NBOX + tid] == 1) ? zdepth[b * NLOCS + loc] : -1000.0f;
    }
    __syncthreads();

    float m = (tid < NBOX) ? sd[tid] : -1e30f;
    red[tid] = m; __syncthreads();
    for (int s = 256; s > 0; s >>= 1) {
        if (tid < s) red[tid] = fmaxf(red[tid], red[tid + s]);
        __syncthreads();
    }
    m = red[0]; __syncthreads();

    float sum = (tid < NBOX) ? expf(sd[tid] - m) : 0.f;
    red[tid] = sum; __syncthreads();
    for (int s = 256; s > 0; s >>= 1) {
        if (tid < s) red[tid] += red[tid + s];
        __syncthreads();
    }
    float inv = 1.0f / red[0];
    __syncthreads();

    if (tid < NBOX) {
        int g = b * NBOX + tid;
        float wv = expf(sd[tid] - m) * inv;   // exp(-1000-m) underflows to exactly 0
        wgt[g] = wv;
        float cx = zwhere[g * 4 + 0], cy = zwhere[g * 4 + 1];
        float w  = zwhere[g * 4 + 2], h  = zwhere[g * 4 + 3];
        float isx = 1.0f / fmaxf(w, 1e-5f);
        float isy = 1.0f / fmaxf(h, 1e-5f);
        float sxv = isx * (63.0f / 127.0f);
        float oxv = 31.5f * (1.0f - 2.0f * cx * isx);
        float syv = isy * (63.0f / 127.0f);
        float oyv = 31.5f * (1.0f - 2.0f * cy * isy);
        sxs[g] = sxv; oxs[g] = oxv; sys[g] = syv; oys[g] = oyv;
        binst[g] = b * NLOCS + loc_of_box(tid);
        int wlo = min(127, max(0, (int)floorf((-1.0f - oxv) / sxv)));
        int whi = max(0, min(127, (int)ceilf((64.0f - oxv) / sxv)));
        int hlo = min(127, max(0, (int)floorf((-1.0f - oyv) / syv)));
        int hhi = max(0, min(127, (int)ceilf((64.0f - oyv) / syv)));
        rect[g] = wlo | (whi << 8) | (hlo << 16) | (hhi << 24);
        sd[tid] = wv;   // presence flag for compaction
    }
    __syncthreads();

    if (tid < 64) {   // wave 0: deterministic ascending compaction
        int base = 0;
        for (int c = 0; c < 6; ++c) {
            int n = c * 64 + tid;
            bool p = (n < NBOX) && (sd[n] > 0.0f);
            unsigned long long mask = __ballot(p);
            int pos = __popcll(mask & ((1ull << tid) - 1ull));
            if (p) cidx[b * NBOX + base + pos] = n;
            base += __popcll(mask);
        }
        if (tid == 0) cnt[b] = base;
    }
}

// Decoder chain for ONE (instance, row-quarter) per block. 512 threads, 8 waves.
// conv_transpose 2x2/s2 has zero output overlap: final rows [16s,16s+16) need
// only L4 rows [8s..+8), L3 [4s..+4), L2 [2s..+2), L1 row s, L0 row s>>1.
// out[(2i+di, 2j+dj)][co] = act( b[co] + sum_k x[i,j][k] * W[1-di][1-dj][k][co] )
// (tap t = 2di+dj, flipped index ft = 3-t).
// NOTE (R8): all register arrays must be static-indexed (full unroll) or they
// spill to scratch.  LDS: 9536 floats = 38,144 B -> 4 blocks/CU.
__global__ __launch_bounds__(512, 4) void decode_fused_k(
    const float* __restrict__ z_what,
    const float* __restrict__ W0, const float* __restrict__ B0,
    const float* __restrict__ W1, const float* __restrict__ B1,
    const float* __restrict__ W2, const float* __restrict__ B2,
    const float* __restrict__ W3, const float* __restrict__ B3,
    const float* __restrict__ W4, const float* __restrict__ B4,
    const float* __restrict__ W5, const float* __restrict__ B5,
    const float* __restrict__ z_where, const int* __restrict__ z_present,
    const float* __restrict__ z_depth,
    float* __restrict__ wgt, float* __restrict__ sxs, float* __restrict__ oxs,
    float* __restrict__ sys, float* __restrict__ oys, int* __restrict__ binst,
    int* __restrict__ rect, int* __restrict__ cidx, int* __restrict__ cnt,
    float* __restrict__ dec)
{
    __shared__ __align__(16) float sm[9536];   // 38,144 B

    const int bid = blockIdx.x;
    if (bid >= SPLIT * NINST) {   // 4 trailing blocks: box params
        box_params_dev(bid - SPLIT * NINST, z_where, z_present, z_depth,
                       wgt, sxs, oxs, sys, oys, binst, rect, cidx, cnt, sm);
        return;
    }
    // s-major: neighbor blocks share the same weight slices (L1/L2 locality)
    const int s    = bid / NINST;          // 0..3  row-quarter
    const int inst = bid - s * NINST;

    float* s_x = sm;            // [64]
    float* aL0 = sm + 64;       // [2 px][256]          L0 row s>>1
    float* aL1 = sm + 576;      // [4 px][128]          L1 row s
    float* aL2 = sm + 1088;     // [2 rows][8 px][64]   L2 rows 2s..2s+1
    float* aL3 = sm + 2112;     // [4 rows*16 px][36]   L3 rows 4s..4s+3 (pad 36)
    float* aL4 = sm + 4416;     // [8 rows*32 px][20]   L4 rows 8s..8s+7 (pad 20)

    const int tid = threadIdx.x;
    const int lane = tid & 63;
    const int wv = __builtin_amdgcn_readfirstlane(tid >> 6);   // 0..7

    if (tid < 64) s_x[tid] = z_what[inst * 64 + tid];
    __syncthreads();

    // ---- L0: K=64 -> 256ch, row r0 = s>>1, cols 0..1.  thread = (col, ch).
    {
        const int c0 = tid & 255;
        const int j0 = __builtin_amdgcn_readfirstlane(tid >> 8);   // 0..1
        const int ft = 3 - (2 * (s >> 1) + j0);
        const float* wp = W0 + (size_t)ft * 64 * 256 + c0;
        float a = 0.f;
        #pragma unroll 8
        for (int k = 0; k < 64; ++k)
            a = fmaf(s_x[k], wp[k * 256], a);
        aL0[j0 * 256 + c0] = fmaxf(a + B0[c0], 0.f);
    }
    __syncthreads();

    // ---- L1: K=256 -> 128ch, row s, cols 0..3.  thread = (col, ch).
    {
        const int c1 = tid & 127;
        const int x1 = __builtin_amdgcn_readfirstlane(tid >> 7);   // 0..3
        const int j = x1 >> 1, dj = x1 & 1, di = s & 1;
        const int ft = 3 - (2 * di + dj);
        const float* wp = W1 + (size_t)ft * 256 * 128 + c1;
        const float* xp = aL0 + j * 256;
        float a = 0.f;
        #pragma unroll 4
        for (int q = 0; q < 64; ++q) {
            float4 xq = *(const float4*)&xp[q * 4];
            a = fmaf(xq.x, wp[(q * 4 + 0) * 128], a);
            a = fmaf(xq.y, wp[(q * 4 + 1) * 128], a);
            a = fmaf(xq.z, wp[(q * 4 + 2) * 128], a);
            a = fmaf(xq.w, wp[(q * 4 + 3) * 128], a);
        }
        aL1[x1 * 128 + c1] = fmaxf(a + B1[c1], 0.f);
    }
    __syncthreads();

    // ---- L2: K=128 -> 64ch, rows 2s..2s+1, cols 0..7.  wave = col, lane = ch.
    {
        const int c2 = lane;
        const int x2 = wv;                       // 0..7
        const int j = x2 >> 1, dj = x2 & 1;
        const float* wA = W2 + (size_t)(3 - dj) * 128 * 64 + c2;   // di=0
        const float* wB = W2 + (size_t)(1 - dj) * 128 * 64 + c2;   // di=1
        const float* xp = aL1 + j * 128;
        float a0 = 0.f, a1 = 0.f;
        #pragma unroll 4
        for (int q = 0; q < 32; ++q) {
            float4 xq = *(const float4*)&xp[q * 4];
            a0 = fmaf(xq.x, wA[(q*4+0)*64], a0); a1 = fmaf(xq.x, wB[(q*4+0)*64], a1);
            a0 = fmaf(xq.y, wA[(q*4+1)*64], a0); a1 = fmaf(xq.y, wB[(q*4+1)*64], a1);
            a0 = fmaf(xq.z, wA[(q*4+2)*64], a0); a1 = fmaf(xq.z, wB[(q*4+2)*64], a1);
            a0 = fmaf(xq.w, wA[(q*4+3)*64], a0); a1 = fmaf(xq.w, wB[(q*4+3)*64], a1);
        }
        float bb = B2[c2];
        aL2[(0 * 8 + x2) * 64 + c2] = fmaxf(a0 + bb, 0.f);
        aL2[(1 * 8 + x2) * 64 + c2] = fmaxf(a1 + bb, 0.f);
    }
    __syncthreads();

    // ---- L3: K=64 -> 32ch, rows 4s..4s+3, cols 0..15.  thread = (col, ch),
    // 4 outputs [i_l][di]; each weight load feeds 2 FMAs.
    {
        const int c3 = tid & 31;
        const int x3 = (tid >> 5) & 15;
        const int j = x3 >> 1, dj = x3 & 1;
        const float* wA = W3 + (size_t)(3 - dj) * 64 * 32 + c3;    // di=0
        const float* wB = W3 + (size_t)(1 - dj) * 64 * 32 + c3;    // di=1
        const float* xp0 = aL2 + (0 * 8 + j) * 64;
        const float* xp1 = aL2 + (1 * 8 + j) * 64;
        float a00 = 0.f, a01 = 0.f, a10 = 0.f, a11 = 0.f;  // [i_l][di]
        #pragma unroll 4
        for (int q = 0; q < 16; ++q) {
            float4 x0 = *(const float4*)&xp0[q * 4];
            float4 x1 = *(const float4*)&xp1[q * 4];
            #pragma unroll
            for (int kk = 0; kk < 4; ++kk) {
                int k = q * 4 + kk;
                float xa = (kk == 0) ? x0.x : (kk == 1) ? x0.y : (kk == 2) ? x0.z : x0.w;
                float xb = (kk == 0) ? x1.x : (kk == 1) ? x1.y : (kk == 2) ? x1.z : x1.w;
                float wa = wA[k * 32], wb = wB[k * 32];
                a00 = fmaf(xa, wa, a00); a01 = fmaf(xa, wb, a01);
                a10 = fmaf(xb, wa, a10); a11 = fmaf(xb, wb, a11);
            }
        }
        float bb = B3[c3];
        aL3[((0) * 16 + x3) * 36 + c3] = fmaxf(a00 + bb, 0.f);   // y3l = 2*i_l+di
        aL3[((1) * 16 + x3) * 36 + c3] = fmaxf(a01 + bb, 0.f);
        aL3[((2) * 16 + x3) * 36 + c3] = fmaxf(a10 + bb, 0.f);
        aL3[((3) * 16 + x3) * 36 + c3] = fmaxf(a11 + bb, 0.f);
    }
    __syncthreads();

    // ---- L4: K=32 -> 16ch, rows 8s..8s+7, cols 0..31.  thread = (col, ch),
    // 8 outputs [i_l 0..3][di]; each weight load feeds 4 FMAs.
    {
        const int c4 = tid & 15;
        const int x4 = (tid >> 4) & 31;
        const int j = x4 >> 1, dj = x4 & 1;
        const float* wA = W4 + (size_t)(3 - dj) * 32 * 16 + c4;    // di=0
        const float* wB = W4 + (size_t)(1 - dj) * 32 * 16 + c4;    // di=1
        float accA[4] = {0.f, 0.f, 0.f, 0.f};   // di=0, i_l 0..3
        float accB[4] = {0.f, 0.f, 0.f, 0.f};   // di=1
        #pragma unroll 2
        for (int q = 0; q < 8; ++q) {
            float4 xr[4];
            #pragma unroll
            for (int il = 0; il < 4; ++il)
                xr[il] = *(const float4*)&aL3[(il * 16 + j) * 36 + q * 4];
            #pragma unroll
            for (int kk = 0; kk < 4; ++kk) {
                int k = q * 4 + kk;
                float wa = wA[k * 16], wb = wB[k * 16];
                #pragma unroll
                for (int il = 0; il < 4; ++il) {
                    float xv = (kk == 0) ? xr[il].x : (kk == 1) ? xr[il].y
                             : (kk == 2) ? xr[il].z : xr[il].w;
                    accA[il] = fmaf(xv, wa, accA[il]);
                    accB[il] = fmaf(xv, wb, accB[il]);
                }
            }
        }
        float bb = B4[c4];
        #pragma unroll
        for (int il = 0; il < 4; ++il) {
            aL4[((2 * il + 0) * 32 + x4) * 20 + c4] = fmaxf(accA[il] + bb, 0.f);
            aL4[((2 * il + 1) * 32 + x4) * 20 + c4] = fmaxf(accB[il] + bb, 0.f);
        }
    }
    __syncthreads();

    // ---- L5: K=16 -> 3ch sigmoid, rows 16s..16s+15, cols 0..63.
    // thread handles px (y5l=wv, x5=lane... tid&63) and (y5l+8, x5): same tap.
    {
        const int x5 = tid & 63;
        const int y5lA = tid >> 6;          // 0..7
        const int i_lA = y5lA >> 1;         // L4 local row
        const int i_lB = i_lA + 4;          // for y5l+8
        const int j = x5 >> 1, dj = x5 & 1, di = y5lA & 1;
        const int ft = 3 - (2 * di + dj);
        const float* wp = W5 + ft * 48;     // [k][3]
        const float* xpA = aL4 + (i_lA * 2 + di) * 0;  // (placeholder, see below)
        // input px for output (y5,x5): i = y5>>1 -> local i_l, j = x5>>1
        float a0A = B5[0], a1A = B5[1], a2A = B5[2];
        float a0B = B5[0], a1B = B5[1], a2B = B5[2];
        #pragma unroll
        for (int k = 0; k < 16; ++k) {
            float xA = aL4[(i_lA * 32 + j) * 20 + k];
            float xB = aL4[(i_lB * 32 + j) * 20 + k];
            float w0 = wp[k * 3 + 0], w1 = wp[k * 3 + 1], w2 = wp[k * 3 + 2];
            a0A = fmaf(xA, w0, a0A); a1A = fmaf(xA, w1, a1A); a2A = fmaf(xA, w2, a2A);
            a0B = fmaf(xB, w0, a0B); a1B = fmaf(xB, w1, a1B); a2B = fmaf(xB, w2, a2B);
        }
        a0A = 1.0f / (1.0f + expf(-a0A)); a1A = 1.0f / (1.0f + expf(-a1A));
        a2A = 1.0f / (1.0f + expf(-a2A));
        a0B = 1.0f / (1.0f + expf(-a0B)); a1B = 1.0f / (1.0f + expf(-a1B));
        a2B = 1.0f / (1.0f + expf(-a2B));
        (void)xpA;
        float* dpA = dec + (size_t)inst * 12288
                   + (size_t)((16 * s + y5lA) * 64 + x5) * 3;
        float* dpB = dec + (size_t)inst * 12288
                   + (size_t)((16 * s + y5lA + 8) * 64 + x5) * 3;
        dpA[0] = a0A; dpA[1] = a1A; dpA[2] = a2A;
        dpB[0] = a0B; dpB[1] = a1B; dpB[2] = a2B;
    }
}

// Fused STN bilinear sample + weighted composite + in-block reduce.
// grid 256 = (b, 16x16 tile); 1024 threads = 4 box-splits x 256 px.
__global__ __launch_bounds__(1024) void composite_k(
    const float* __restrict__ dec, const float* __restrict__ wgt,
    const float* __restrict__ sxs, const float* __restrict__ oxs,
    const float* __restrict__ sys, const float* __restrict__ oys,
    const int* __restrict__ binst, const int* __restrict__ rect,
    const int* __restrict__ cidx, const int* __restrict__ cnt,
    float* __restrict__ out)
{
    __shared__ float pls[4][256][3];   // 12 KB

    int b = blockIdx.x >> 6, tile = blockIdx.x & 63;
    int tx0 = (tile & 7) << 4, ty0 = (tile >> 3) << 4;
    int s = threadIdx.x >> 8, px = threadIdx.x & 255;
    int lx = px & 15, ly = px >> 4;
    int w = tx0 + lx, h = ty0 + ly;

    int nb = cnt[b];
    int lo = (nb * s) >> 2, hi = (nb * (s + 1)) >> 2;

    float fw = (float)w, fh = (float)h;
    float a0 = 0.f, a1 = 0.f, a2 = 0.f;
    for (int q = lo; q < hi; ++q) {
        int n = cidx[b * NBOX + q];
        int rc = rect[b * NBOX + n];
        int wlo = rc & 255, whi = (rc >> 8) & 255;
        int hlo = (rc >> 16) & 255, hhi = (rc >> 24) & 255;
        if (whi < tx0 || wlo > tx0 + 15 || hhi < ty0 || hlo > ty0 + 15) continue;
        int g = b * NBOX + n;
        float wg = wgt[g];
        float pxx = fmaf(fw, sxs[g], oxs[g]);
        float pyy = fmaf(fh, sys[g], oys[g]);
        float x0 = floorf(pxx), y0 = floorf(pyy);
        if (x0 < -1.0f || x0 > 63.0f || y0 < -1.0f || y0 > 63.0f) continue;
        float wx = pxx - x0, wy = pyy - y0;
        int ix = (int)x0, iy = (int)y0;
        int x0c = max(ix, 0), x1c = min(ix + 1, 63);
        int y0c = max(iy, 0), y1c = min(iy + 1, 63);
        float m00 = (ix >= 0 && iy >= 0) ? 1.f : 0.f;
        float m01 = (ix + 1 <= 63 && iy >= 0) ? 1.f : 0.f;
        float m10 = (ix >= 0 && iy + 1 <= 63) ? 1.f : 0.f;
        float m11 = (ix + 1 <= 63 && iy + 1 <= 63) ? 1.f : 0.f;
        float w00 = (1.f - wy) * (1.f - wx) * m00;
        float w01 = (1.f - wy) * wx * m01;
        float w10 = wy * (1.f - wx) * m10;
        float w11 = wy * wx * m11;
        const float* img = dec + (size_t)binst[g] * 12288;   // (64,64,3) HWC
        int b00 = (y0c * 64 + x0c) * 3, b01 = (y0c * 64 + x1c) * 3;
        int b10 = (y1c * 64 + x0c) * 3, b11 = (y1c * 64 + x1c) * 3;
        a0 += wg * (w00 * img[b00]   + w01 * img[b01]   + w10 * img[b10]   + w11 * img[b11]);
        a1 += wg * (w00 * img[b00+1] + w01 * img[b01+1] + w10 * img[b10+1] + w11 * img[b11+1]);
        a2 += wg * (w00 * img[b00+2] + w01 * img[b01+2] + w10 * img[b10+2] + w11 * img[b11+2]);
    }
    pls[s][px][0] = a0; pls[s][px][1] = a1; pls[s][px][2] = a2;
    __syncthreads();

    if (threadIdx.x < 768) {
        int c = threadIdx.x >> 8, p2 = threadIdx.x & 255;
        float v = pls[0][p2][c] + pls[1][p2][c] + pls[2][p2][c] + pls[3][p2][c];
        int h2 = ty0 + (p2 >> 4), w2 = tx0 + (p2 & 15);
        out[((b * 3 + c) * 128 + h2) * 128 + w2] = v;
    }
}

extern "C" void kernel_launch(void* const* d_in, const int* in_sizes, int n_in,
                              void* d_out, int out_size, void* d_ws, size_t ws_size,
                              hipStream_t stream)
{
    const float* z_what    = (const float*)d_in[0];   // (4,85,64)
    const float* z_where   = (const float*)d_in[1];   // (4,380,4)
    const int*   z_present = (const int*)  d_in[2];   // (4,380,1)
    const float* z_depth   = (const float*)d_in[3];   // (4,85,1)

    // workspace: dec 16.71 MB | params ~55 KB
    char* ws = (char*)d_ws;
    float* dec = (float*)ws;                           // 340*12288 f32
    float* P   = (float*)(ws + 16711680);
    float* wgt = P,        *sxs = P + 1520, *oxs = P + 2 * 1520;
    float* sys = P + 3 * 1520, *oys = P + 4 * 1520;
    int* binst = (int*)(P + 5 * 1520);
    int* rect  = binst + 1520;
    int* cidx  = binst + 2 * 1520;
    int* cnt   = binst + 3 * 1520;

    decode_fused_k<<<dim3(SPLIT * NINST + 4), dim3(512), 0, stream>>>(
        z_what,
        (const float*)d_in[4],  (const float*)d_in[5],
        (const float*)d_in[6],  (const float*)d_in[7],
        (const float*)d_in[8],  (const float*)d_in[9],
        (const float*)d_in[10], (const float*)d_in[11],
        (const float*)d_in[12], (const float*)d_in[13],
        (const float*)d_in[14], (const float*)d_in[15],
        z_where, z_present, z_depth,
        wgt, sxs, oxs, sys, oys, binst, rect, cidx, cnt,
        dec);

    composite_k<<<dim3(256), dim3(1024), 0, stream>>>(
        dec, wgt, sxs, oxs, sys, oys, binst, rect, cidx, cnt, (float*)d_out);
}

// Round 11
// 92.467 us; speedup vs baseline: 1.3771x; 1.3771x over previous
//
#include <hip/hip_runtime.h>
#include <hip/hip_bf16.h>

#define NBOX  380
#define NLOCS 85
#define NINST 340   // B(4) * NLOCS(85)
#define SPLIT 2     // row-half split of each decoder instance

// box index -> location index (from _recon_indices structure)
__device__ __forceinline__ int loc_of_box(int n) {
    if (n < 256) return n >> 2;               // fm=8, 4 boxes/loc
    if (n < 352) return 64 + (n - 256) / 6;   // fm=4, 6 boxes/loc
    if (n < 376) return 80 + (n - 352) / 6;   // fm=2, 6 boxes/loc
    return 84;                                // fm=1, 4 boxes/loc
}

// Per-batch softmax over depths + per-box affine params + rect + compaction.
// 512 threads. Uses sm[0..896).
__device__ void box_params_dev(int b, const float* __restrict__ zwhere,
    const int* __restrict__ zpresent, const float* __restrict__ zdepth,
    float* wgt, float* sxs, float* oxs, float* sys, float* oys,
    int* binst, int* rect, int* cidx, int* cnt, float* sm)
{
    float* sd  = sm;         // 384 (380 used)
    float* red = sm + 384;   // 512
    const int tid = threadIdx.x;

    if (tid < NBOX) {
        int loc = loc_of_box(tid);
        sd[tid] = (zpresent[b * NBOX + tid] == 1) ? zdepth[b * NLOCS + loc] : -1000.0f;
    }
    __syncthreads();

    float m = (tid < NBOX) ? sd[tid] : -1e30f;
    red[tid] = m; __syncthreads();
    for (int s = 256; s > 0; s >>= 1) {
        if (tid < s) red[tid] = fmaxf(red[tid], red[tid + s]);
        __syncthreads();
    }
    m = red[0]; __syncthreads();

    float sum = (tid < NBOX) ? expf(sd[tid] - m) : 0.f;
    red[tid] = sum; __syncthreads();
    for (int s = 256; s > 0; s >>= 1) {
        if (tid < s) red[tid] += red[tid + s];
        __syncthreads();
    }
    float inv = 1.0f / red[0];
    __syncthreads();

    if (tid < NBOX) {
        int g = b * NBOX + tid;
        float wv = expf(sd[tid] - m) * inv;   // exp(-1000-m) underflows to exactly 0
        wgt[g] = wv;
        float cx = zwhere[g * 4 + 0], cy = zwhere[g * 4 + 1];
        float w  = zwhere[g * 4 + 2], h  = zwhere[g * 4 + 3];
        float isx = 1.0f / fmaxf(w, 1e-5f);
        float isy = 1.0f / fmaxf(h, 1e-5f);
        float sxv = isx * (63.0f / 127.0f);
        float oxv = 31.5f * (1.0f - 2.0f * cx * isx);
        float syv = isy * (63.0f / 127.0f);
        float oyv = 31.5f * (1.0f - 2.0f * cy * isy);
        sxs[g] = sxv; oxs[g] = oxv; sys[g] = syv; oys[g] = oyv;
        binst[g] = b * NLOCS + loc_of_box(tid);
        int wlo = min(127, max(0, (int)floorf((-1.0f - oxv) / sxv)));
        int whi = max(0, min(127, (int)ceilf((64.0f - oxv) / sxv)));
        int hlo = min(127, max(0, (int)floorf((-1.0f - oyv) / syv)));
        int hhi = max(0, min(127, (int)ceilf((64.0f - oyv) / syv)));
        rect[g] = wlo | (whi << 8) | (hlo << 16) | (hhi << 24);
        sd[tid] = wv;   // presence flag for compaction
    }
    __syncthreads();

    if (tid < 64) {   // wave 0: deterministic ascending compaction
        int base = 0;
        for (int c = 0; c < 6; ++c) {
            int n = c * 64 + tid;
            bool p = (n < NBOX) && (sd[n] > 0.0f);
            unsigned long long mask = __ballot(p);
            int pos = __popcll(mask & ((1ull << tid) - 1ull));
            if (p) cidx[b * NBOX + base + pos] = n;
            base += __popcll(mask);
        }
        if (tid == 0) cnt[b] = base;
    }
}

// Decoder chain for ONE (instance, row-HALF) per block. 512 threads, 8 waves.
// Final rows [32s,32s+32) need L4 rows [16s..+16), L3 [8s..+8), L2 [4s..+4),
// L1 [2s..+2), L0 row s.  Zero output overlap in 2x2/s2 conv_transpose.
// out[(2i+di, 2j+dj)][co] = act( b[co] + sum_k x[i,j][k] * W[1-di][1-dj][k][co] )
// R10 lesson: keep per-thread ILP >= 2 in every phase (di-pair accumulators);
// R8 lesson: register arrays must be static-indexed (FULL unroll only).
// LDS 53,248 B -> 3 blocks/CU -> all 680+4 blocks co-resident.
__global__ __launch_bounds__(512, 2) void decode_fused_k(
    const float* __restrict__ z_what,
    const float* __restrict__ W0, const float* __restrict__ B0,
    const float* __restrict__ W1, const float* __restrict__ B1,
    const float* __restrict__ W2, const float* __restrict__ B2,
    const float* __restrict__ W3, const float* __restrict__ B3,
    const float* __restrict__ W4, const float* __restrict__ B4,
    const float* __restrict__ W5, const float* __restrict__ B5,
    const float* __restrict__ z_where, const int* __restrict__ z_present,
    const float* __restrict__ z_depth,
    float* __restrict__ wgt, float* __restrict__ sxs, float* __restrict__ oxs,
    float* __restrict__ sys, float* __restrict__ oys, int* __restrict__ binst,
    int* __restrict__ rect, int* __restrict__ cidx, int* __restrict__ cnt,
    float* __restrict__ dec)
{
    __shared__ __align__(16) float sm[13312];   // 53,248 B

    const int bid = blockIdx.x;
    if (bid >= SPLIT * NINST) {   // 4 trailing blocks: box params
        box_params_dev(bid - SPLIT * NINST, z_where, z_present, z_depth,
                       wgt, sxs, oxs, sys, oys, binst, rect, cidx, cnt, sm);
        return;
    }
    const int s    = bid / NINST;          // 0..1  row-half
    const int inst = bid - s * NINST;

    // LDS overlay: region A [0,8704) = {s_x, aL0, aL1, aL2} then aL4;
    //              region B [8704,13312) = aL3.
    float* s_x = sm;            // [64]
    float* aL0 = sm + 64;       // [2 cols][256]           L0 row s
    float* aL1 = sm + 576;      // [2 rows * 4 cols][128]  L1 rows 2s..2s+1
    float* aL2 = sm + 1600;     // [4 rows * 8 cols][64]   L2 rows 4s..4s+3
    float* aL4 = sm;            // [16 rows * 32 cols][17] L4 rows 16s..16s+15
    float* aL3 = sm + 8704;     // [8 rows * 16 cols][36]  L3 rows 8s..8s+7

    const int tid = threadIdx.x;

    if (tid < 64) s_x[tid] = z_what[inst * 64 + tid];
    __syncthreads();

    // ---- L0: K=64 -> 256ch, need row s, cols 0..1. thread = (col j0, ch).
    {
        const int c0 = tid & 255;
        const int j0 = tid >> 8;                 // 0..1
        const int ft = 3 - (2 * s + j0);         // di = s
        const float* wp = W0 + (size_t)ft * 64 * 256 + c0;
        float a = 0.f;
        #pragma unroll 8
        for (int k = 0; k < 64; ++k)
            a = fmaf(s_x[k], wp[k * 256], a);
        aL0[j0 * 256 + c0] = fmaxf(a + B0[c0], 0.f);
    }
    __syncthreads();

    // ---- L1: K=256 -> 128ch, rows 2s..2s+1 (di=0,1), cols 0..3.
    // thread = (x1, ch): 2 accs (di pair), x load reused 2x.
    {
        const int c1 = tid & 127;
        const int x1 = tid >> 7;                 // 0..3
        const int j = x1 >> 1, dj = x1 & 1;
        const float* wA = W1 + (size_t)(3 - dj) * 256 * 128 + c1;   // di=0
        const float* wB = W1 + (size_t)(1 - dj) * 256 * 128 + c1;   // di=1
        const float* xp = aL0 + j * 256;
        float a0 = 0.f, a1 = 0.f;
        #pragma unroll 4
        for (int q = 0; q < 64; ++q) {
            float4 xq = *(const float4*)&xp[q * 4];
            a0 = fmaf(xq.x, wA[(q*4+0)*128], a0); a1 = fmaf(xq.x, wB[(q*4+0)*128], a1);
            a0 = fmaf(xq.y, wA[(q*4+1)*128], a0); a1 = fmaf(xq.y, wB[(q*4+1)*128], a1);
            a0 = fmaf(xq.z, wA[(q*4+2)*128], a0); a1 = fmaf(xq.z, wB[(q*4+2)*128], a1);
            a0 = fmaf(xq.w, wA[(q*4+3)*128], a0); a1 = fmaf(xq.w, wB[(q*4+3)*128], a1);
        }
        float bb = B1[c1];
        aL1[(0 * 4 + x1) * 128 + c1] = fmaxf(a0 + bb, 0.f);   // local row di=0
        aL1[(1 * 4 + x1) * 128 + c1] = fmaxf(a1 + bb, 0.f);   // local row di=1
    }
    __syncthreads();

    // ---- L2: K=128 -> 64ch, rows 4s..4s+3, cols 0..7.
    // thread = (x2, ch): 4 accs [i_l 0..1][di 0..1].
    {
        const int c2 = tid & 63;
        const int x2 = tid >> 6;                 // 0..7
        const int j = x2 >> 1, dj = x2 & 1;
        const float* wA = W2 + (size_t)(3 - dj) * 128 * 64 + c2;
        const float* wB = W2 + (size_t)(1 - dj) * 128 * 64 + c2;
        const float* xp0 = aL1 + (0 * 4 + j) * 128;
        const float* xp1 = aL1 + (1 * 4 + j) * 128;
        float a00 = 0.f, a01 = 0.f, a10 = 0.f, a11 = 0.f;    // [i_l][di]
        #pragma unroll 4
        for (int q = 0; q < 32; ++q) {
            float4 x0 = *(const float4*)&xp0[q * 4];
            float4 x1 = *(const float4*)&xp1[q * 4];
            #pragma unroll
            for (int kk = 0; kk < 4; ++kk) {
                int k = q * 4 + kk;
                float xa = (kk==0)?x0.x:(kk==1)?x0.y:(kk==2)?x0.z:x0.w;
                float xb = (kk==0)?x1.x:(kk==1)?x1.y:(kk==2)?x1.z:x1.w;
                float wa = wA[k * 64], wb = wB[k * 64];
                a00 = fmaf(xa, wa, a00); a01 = fmaf(xa, wb, a01);
                a10 = fmaf(xb, wa, a10); a11 = fmaf(xb, wb, a11);
            }
        }
        float bb = B2[c2];
        aL2[(0 * 8 + x2) * 64 + c2] = fmaxf(a00 + bb, 0.f);
        aL2[(1 * 8 + x2) * 64 + c2] = fmaxf(a01 + bb, 0.f);
        aL2[(2 * 8 + x2) * 64 + c2] = fmaxf(a10 + bb, 0.f);
        aL2[(3 * 8 + x2) * 64 + c2] = fmaxf(a11 + bb, 0.f);
    }
    __syncthreads();

    // ---- L3: K=64 -> 32ch, rows 8s..8s+7, cols 0..15.
    // thread = (x3, ch): 8 accs [i_l 0..3][di].
    {
        const int c3 = tid & 31;
        const int x3 = tid >> 5;                 // 0..15
        const int j = x3 >> 1, dj = x3 & 1;
        const float* wA = W3 + (size_t)(3 - dj) * 64 * 32 + c3;
        const float* wB = W3 + (size_t)(1 - dj) * 64 * 32 + c3;
        float accA[4], accB[4];
        #pragma unroll
        for (int il = 0; il < 4; ++il) { accA[il] = 0.f; accB[il] = 0.f; }
        #pragma unroll
        for (int q = 0; q < 16; ++q) {
            float4 xr[4];
            #pragma unroll
            for (int il = 0; il < 4; ++il)
                xr[il] = *(const float4*)&aL2[(il * 8 + j) * 64 + q * 4];
            #pragma unroll
            for (int kk = 0; kk < 4; ++kk) {
                int k = q * 4 + kk;
                float wa = wA[k * 32], wb = wB[k * 32];
                #pragma unroll
                for (int il = 0; il < 4; ++il) {
                    float xv = (kk==0)?xr[il].x:(kk==1)?xr[il].y:(kk==2)?xr[il].z:xr[il].w;
                    accA[il] = fmaf(xv, wa, accA[il]);
                    accB[il] = fmaf(xv, wb, accB[il]);
                }
            }
        }
        float bb = B3[c3];
        #pragma unroll
        for (int il = 0; il < 4; ++il) {
            aL3[((2 * il + 0) * 16 + x3) * 36 + c3] = fmaxf(accA[il] + bb, 0.f);
            aL3[((2 * il + 1) * 16 + x3) * 36 + c3] = fmaxf(accB[il] + bb, 0.f);
        }
    }
    __syncthreads();

    // ---- L4: K=32 -> 16ch, rows 16s..16s+15, cols 0..31.
    // thread = (x4, ch): 16 accs [i_l 0..7][di].
    {
        const int c4 = tid & 15;
        const int x4 = tid >> 4;                 // 0..31
        const int j = x4 >> 1, dj = x4 & 1;
        const float* wA = W4 + (size_t)(3 - dj) * 32 * 16 + c4;
        const float* wB = W4 + (size_t)(1 - dj) * 32 * 16 + c4;
        float accA[8], accB[8];
        #pragma unroll
        for (int il = 0; il < 8; ++il) { accA[il] = 0.f; accB[il] = 0.f; }
        #pragma unroll
        for (int q = 0; q < 8; ++q) {
            float4 xr[8];
            #pragma unroll
            for (int il = 0; il < 8; ++il)
                xr[il] = *(const float4*)&aL3[(il * 16 + j) * 36 + q * 4];
            #pragma unroll
            for (int kk = 0; kk < 4; ++kk) {
                int k = q * 4 + kk;
                float wa = wA[k * 16], wb = wB[k * 16];
                #pragma unroll
                for (int il = 0; il < 8; ++il) {
                    float xv = (kk==0)?xr[il].x:(kk==1)?xr[il].y:(kk==2)?xr[il].z:xr[il].w;
                    accA[il] = fmaf(xv, wa, accA[il]);
                    accB[il] = fmaf(xv, wb, accB[il]);
                }
            }
        }
        float bb = B4[c4];
        #pragma unroll
        for (int il = 0; il < 8; ++il) {
            aL4[((2 * il + 0) * 32 + x4) * 17 + c4] = fmaxf(accA[il] + bb, 0.f);
            aL4[((2 * il + 1) * 32 + x4) * 17 + c4] = fmaxf(accB[il] + bb, 0.f);
        }
    }
    __syncthreads();

    // ---- L5: K=16 -> 3ch sigmoid, rows 32s..32s+31, cols 0..63.
    // lane = x5, group g = tid>>6: rows g, g+8, g+16, g+24 (same di = g&1).
    {
        const int x5 = tid & 63;
        const int g  = tid >> 6;                 // 0..7
        const int j = x5 >> 1, dj = x5 & 1, di = g & 1;
        const int ft = 3 - (2 * di + dj);
        const float* wp = W5 + ft * 48;          // [k][3]
        float ar[4][3];
        #pragma unroll
        for (int r = 0; r < 4; ++r) { ar[r][0] = B5[0]; ar[r][1] = B5[1]; ar[r][2] = B5[2]; }
        #pragma unroll
        for (int k = 0; k < 16; ++k) {
            float w0 = wp[k * 3 + 0], w1 = wp[k * 3 + 1], w2 = wp[k * 3 + 2];
            #pragma unroll
            for (int r = 0; r < 4; ++r) {
                int y5l = g + 8 * r;             // local output row
                float xv = aL4[((y5l >> 1) * 32 + j) * 17 + k];
                ar[r][0] = fmaf(xv, w0, ar[r][0]);
                ar[r][1] = fmaf(xv, w1, ar[r][1]);
                ar[r][2] = fmaf(xv, w2, ar[r][2]);
            }
        }
        #pragma unroll
        for (int r = 0; r < 4; ++r) {
            int y5l = g + 8 * r;
            float v0 = 1.0f / (1.0f + expf(-ar[r][0]));
            float v1 = 1.0f / (1.0f + expf(-ar[r][1]));
            float v2 = 1.0f / (1.0f + expf(-ar[r][2]));
            float* dp = dec + (size_t)inst * 12288
                      + (size_t)((32 * s + y5l) * 64 + x5) * 3;
            dp[0] = v0; dp[1] = v1; dp[2] = v2;
        }
    }
}

// Fused STN bilinear sample + weighted composite + in-block reduce.
// grid 512 = (b, 16x8 px tile); 1024 threads = 8 box-splits x 128 px.
__global__ __launch_bounds__(1024) void composite_k(
    const float* __restrict__ dec, const float* __restrict__ wgt,
    const float* __restrict__ sxs, const float* __restrict__ oxs,
    const float* __restrict__ sys, const float* __restrict__ oys,
    const int* __restrict__ binst, const int* __restrict__ rect,
    const int* __restrict__ cidx, const int* __restrict__ cnt,
    float* __restrict__ out)
{
    __shared__ float pls[8][128][3];   // 12 KB

    int b = blockIdx.x >> 7, tile = blockIdx.x & 127;      // 8 x-tiles x 16 y-tiles
    int tx0 = (tile & 7) << 4, ty0 = (tile >> 3) << 3;     // 16 wide x 8 tall
    int s = threadIdx.x >> 7, px = threadIdx.x & 127;
    int lx = px & 15, ly = px >> 4;                        // 16 x 8
    int w = tx0 + lx, h = ty0 + ly;

    int nb = cnt[b];
    int lo = (nb * s) >> 3, hi = (nb * (s + 1)) >> 3;

    float fw = (float)w, fh = (float)h;
    float a0 = 0.f, a1 = 0.f, a2 = 0.f;
    for (int q = lo; q < hi; ++q) {
        int n = cidx[b * NBOX + q];
        int rc = rect[b * NBOX + n];
        int wlo = rc & 255, whi = (rc >> 8) & 255;
        int hlo = (rc >> 16) & 255, hhi = (rc >> 24) & 255;
        if (whi < tx0 || wlo > tx0 + 15 || hhi < ty0 || hlo > ty0 + 7) continue;
        int g = b * NBOX + n;
        float wg = wgt[g];
        float pxx = fmaf(fw, sxs[g], oxs[g]);
        float pyy = fmaf(fh, sys[g], oys[g]);
        float x0 = floorf(pxx), y0 = floorf(pyy);
        if (x0 < -1.0f || x0 > 63.0f || y0 < -1.0f || y0 > 63.0f) continue;
        float wx = pxx - x0, wy = pyy - y0;
        int ix = (int)x0, iy = (int)y0;
        int x0c = max(ix, 0), x1c = min(ix + 1, 63);
        int y0c = max(iy, 0), y1c = min(iy + 1, 63);
        float m00 = (ix >= 0 && iy >= 0) ? 1.f : 0.f;
        float m01 = (ix + 1 <= 63 && iy >= 0) ? 1.f : 0.f;
        float m10 = (ix >= 0 && iy + 1 <= 63) ? 1.f : 0.f;
        float m11 = (ix + 1 <= 63 && iy + 1 <= 63) ? 1.f : 0.f;
        float w00 = (1.f - wy) * (1.f - wx) * m00;
        float w01 = (1.f - wy) * wx * m01;
        float w10 = wy * (1.f - wx) * m10;
        float w11 = wy * wx * m11;
        const float* img = dec + (size_t)binst[g] * 12288;   // (64,64,3) HWC
        int b00 = (y0c * 64 + x0c) * 3, b01 = (y0c * 64 + x1c) * 3;
        int b10 = (y1c * 64 + x0c) * 3, b11 = (y1c * 64 + x1c) * 3;
        a0 += wg * (w00 * img[b00]   + w01 * img[b01]   + w10 * img[b10]   + w11 * img[b11]);
        a1 += wg * (w00 * img[b00+1] + w01 * img[b01+1] + w10 * img[b10+1] + w11 * img[b11+1]);
        a2 += wg * (w00 * img[b00+2] + w01 * img[b01+2] + w10 * img[b10+2] + w11 * img[b11+2]);
    }
    pls[s][px][0] = a0; pls[s][px][1] = a1; pls[s][px][2] = a2;
    __syncthreads();

    if (threadIdx.x < 384) {
        int c = threadIdx.x >> 7, p2 = threadIdx.x & 127;
        float v = 0.f;
        #pragma unroll
        for (int t = 0; t < 8; ++t) v += pls[t][p2][c];
        int h2 = ty0 + (p2 >> 4), w2 = tx0 + (p2 & 15);
        out[((b * 3 + c) * 128 + h2) * 128 + w2] = v;
    }
}

extern "C" void kernel_launch(void* const* d_in, const int* in_sizes, int n_in,
                              void* d_out, int out_size, void* d_ws, size_t ws_size,
                              hipStream_t stream)
{
    const float* z_what    = (const float*)d_in[0];   // (4,85,64)
    const float* z_where   = (const float*)d_in[1];   // (4,380,4)
    const int*   z_present = (const int*)  d_in[2];   // (4,380,1)
    const float* z_depth   = (const float*)d_in[3];   // (4,85,1)

    // workspace: dec 16.71 MB | params ~55 KB
    char* ws = (char*)d_ws;
    float* dec = (float*)ws;                           // 340*12288 f32
    float* P   = (float*)(ws + 16711680);
    float* wgt = P,        *sxs = P + 1520, *oxs = P + 2 * 1520;
    float* sys = P + 3 * 1520, *oys = P + 4 * 1520;
    int* binst = (int*)(P + 5 * 1520);
    int* rect  = binst + 1520;
    int* cidx  = binst + 2 * 1520;
    int* cnt   = binst + 3 * 1520;

    decode_fused_k<<<dim3(SPLIT * NINST + 4), dim3(512), 0, stream>>>(
        z_what,
        (const float*)d_in[4],  (const float*)d_in[5],
        (const float*)d_in[6],  (const float*)d_in[7],
        (const float*)d_in[8],  (const float*)d_in[9],
        (const float*)d_in[10], (const float*)d_in[11],
        (const float*)d_in[12], (const float*)d_in[13],
        (const float*)d_in[14], (const float*)d_in[15],
        z_where, z_present, z_depth,
        wgt, sxs, oxs, sys, oys, binst, rect, cidx, cnt,
        dec);

    composite_k<<<dim3(512), dim3(1024), 0, stream>>>(
        dec, wgt, sxs, oxs, sys, oys, binst, rect, cidx, cnt, (float*)d_out);
}